// Round 1
// baseline (191.975 us; speedup 1.0000x reference)
//
#include <hip/hip_runtime.h>
#include <hip/hip_bf16.h>
#include <cstdint>
#include <cstddef>

// ---------------------------------------------------------------------------
// MultiHeadAttention: B=2, S=2048, E=1024, H=16, D=64. fp32 in/out.
// Pipeline: cvt(f32->bf16) -> QKV GEMM (scatter Q,K,V^T bf16) -> flash attn
//           -> out GEMM (fp32 + bias).
// ---------------------------------------------------------------------------

typedef float f32x4 __attribute__((ext_vector_type(4)));
typedef short s16x8 __attribute__((ext_vector_type(8)));

#define AS1C(p) ((const __attribute__((address_space(1))) void*)(p))
#define AS3(p)  ((__attribute__((address_space(3))) void*)(p))

__device__ __forceinline__ unsigned short f2bf(float f) {
    union { float f; unsigned u; } v; v.f = f;
    return (unsigned short)((v.u + 0x7FFFu + ((v.u >> 16) & 1u)) >> 16);
}

// ---------------------------------------------------------------------------
// fp32 -> bf16 convert (vectorized, n divisible by 4)
// ---------------------------------------------------------------------------
__global__ void cvt_bf16(const float* __restrict__ src,
                         unsigned short* __restrict__ dst, int n4) {
    int i = blockIdx.x * blockDim.x + threadIdx.x;
    if (i >= n4) return;
    float4 f = reinterpret_cast<const float4*>(src)[i];
    ushort4 o;
    o.x = f2bf(f.x); o.y = f2bf(f.y); o.z = f2bf(f.z); o.w = f2bf(f.w);
    reinterpret_cast<ushort4*>(dst)[i] = o;
}

// ---------------------------------------------------------------------------
// GEMM: C[M,N] = A[M,K] @ B[N,K]^T + bias[N]
// A,B bf16 row-major (K contiguous). 128x128 tile, BK=32, 4 waves (2x2),
// each wave 64x64 via 4x4 grid of 16x16x32 MFMA fragments.
// MODE 0: scatter bf16 into Q[b,h,s,d], K[b,h,s,d], Vt[b,h,d,s]  (N=3072)
// MODE 1: fp32 store to Cf[M,N]
// ---------------------------------------------------------------------------
template <int MODE>
__global__ __launch_bounds__(256, 2)
void gemm_bt(const unsigned short* __restrict__ A,
             const unsigned short* __restrict__ B,
             const float* __restrict__ bias,
             float* __restrict__ Cf,
             unsigned short* __restrict__ Qw,
             unsigned short* __restrict__ Kw,
             unsigned short* __restrict__ Vtw,
             int M, int N, int K) {
    constexpr int BK = 32;
    __shared__ unsigned short As[128 * BK];
    __shared__ unsigned short Bs[128 * BK];

    const int tid = threadIdx.x;
    const int wid = tid >> 6, lane = tid & 63;
    const int brow = blockIdx.y * 128, bcol = blockIdx.x * 128;
    const int wr = wid >> 1, wc = wid & 1;

    f32x4 acc[4][4] = {};

    const int kIters = K / BK;
    for (int kt = 0; kt < kIters; ++kt) {
        // ---- stage A,B tiles: LDS linear [128][32] bf16 (64B rows) ----
#pragma unroll
        for (int i = 0; i < 2; ++i) {
            const int lb = (wid * 2 + i) * 1024;        // wave-uniform LDS byte base
            const int row = (lb >> 6) + (lane >> 2);    // 64B per row
            const int inrow = (lane & 3) * 16;
            const char* ga = (const char*)A + ((size_t)(brow + row) * K + kt * BK) * 2 + inrow;
            __builtin_amdgcn_global_load_lds(AS1C(ga), AS3((char*)As + lb), 16, 0, 0);
            const char* gb = (const char*)B + ((size_t)(bcol + row) * K + kt * BK) * 2 + inrow;
            __builtin_amdgcn_global_load_lds(AS1C(gb), AS3((char*)Bs + lb), 16, 0, 0);
        }
        __syncthreads();

        s16x8 af[4], bfr[4];
#pragma unroll
        for (int f = 0; f < 4; ++f) {
            af[f]  = *(const s16x8*)((const char*)As + (wr * 64 + f * 16 + (lane & 15)) * 64 + (lane >> 4) * 16);
            bfr[f] = *(const s16x8*)((const char*)Bs + (wc * 64 + f * 16 + (lane & 15)) * 64 + (lane >> 4) * 16);
        }
#pragma unroll
        for (int mf = 0; mf < 4; ++mf)
#pragma unroll
            for (int nf = 0; nf < 4; ++nf)
                acc[mf][nf] = __builtin_amdgcn_mfma_f32_16x16x32_bf16(af[mf], bfr[nf], acc[mf][nf], 0, 0, 0);
        __syncthreads();
    }

    // ---- epilogue ----
    float bv[4];
#pragma unroll
    for (int nf = 0; nf < 4; ++nf) bv[nf] = bias[bcol + wc * 64 + nf * 16 + (lane & 15)];

#pragma unroll
    for (int mf = 0; mf < 4; ++mf) {
#pragma unroll
        for (int r = 0; r < 4; ++r) {
            const int row = brow + wr * 64 + mf * 16 + (lane >> 4) * 4 + r;
#pragma unroll
            for (int nf = 0; nf < 4; ++nf) {
                const int col = bcol + wc * 64 + nf * 16 + (lane & 15);
                float v = acc[mf][nf][r] + bv[nf];
                if constexpr (MODE == 0) {
                    const int which = col >> 10, e = col & 1023;
                    const int h = e >> 6, d = e & 63;
                    const int b = row >> 11, s = row & 2047;
                    const size_t bh = (size_t)(b * 16 + h);
                    unsigned short x = f2bf(v);
                    if (which == 0)      Qw[(bh * 2048 + s) * 64 + d] = x;
                    else if (which == 1) Kw[(bh * 2048 + s) * 64 + d] = x;
                    else                 Vtw[(bh * 64 + d) * 2048 + s] = x;
                } else {
                    Cf[(size_t)row * N + col] = v;
                }
            }
        }
    }
}

// ---------------------------------------------------------------------------
// Flash attention fwd. Grid: (qtile=16, bh=32). Block: 256 threads (4 waves),
// each wave owns 32 q-rows. K/V chunks of 64 keys staged in LDS (XOR-swizzled
// via pre-swizzled global source, rule #21). Online softmax in registers.
// ---------------------------------------------------------------------------
__global__ __launch_bounds__(256, 2)
void attn_fwd(const unsigned short* __restrict__ Q,   // [32][2048][64]
              const unsigned short* __restrict__ Kk,  // [32][2048][64]
              const unsigned short* __restrict__ Vt,  // [32][64][2048]
              unsigned short* __restrict__ O) {       // [4096][1024] (B,S,E)
    constexpr float SCALE = 0.125f;  // 1/sqrt(64)
    __shared__ unsigned short Ks[64 * 64];       // [key][d] swizzled, 8KB
    __shared__ unsigned short Vs[64 * 64];       // [d][key] swizzled, 8KB
    __shared__ unsigned short Ps[4 * 32 * 64];   // per-wave P [32][64] swizzled, 16KB

    const int tid = threadIdx.x;
    const int wid = tid >> 6, lane = tid & 63;
    const int bh = blockIdx.y;
    const int b = bh >> 4, h = bh & 15;
    const int q0 = blockIdx.x * 128 + wid * 32;  // first q row for this wave

    const char* Qb  = (const char*)(Q  + (size_t)bh * 2048 * 64);
    const char* Kb  = (const char*)(Kk + (size_t)bh * 2048 * 64);
    const char* Vtb = (const char*)(Vt + (size_t)bh * 64 * 2048);
    char* PsW = (char*)Ps + wid * 4096;          // this wave's P region (32*64*2B)

    // Q fragments: aq[mf][kf], rows q0+mf*16+(lane&15), k = kf*32+(lane>>4)*8
    s16x8 aq[2][2];
#pragma unroll
    for (int mf = 0; mf < 2; ++mf)
#pragma unroll
        for (int kf = 0; kf < 2; ++kf)
            aq[mf][kf] = *(const s16x8*)(Qb + (size_t)(q0 + mf * 16 + (lane & 15)) * 128 +
                                         (kf * 32 + (lane >> 4) * 8) * 2);

    float m_i[2][4], l_i[2][4];
    f32x4 o_acc[2][4] = {};
#pragma unroll
    for (int mf = 0; mf < 2; ++mf)
#pragma unroll
        for (int r = 0; r < 4; ++r) { m_i[mf][r] = -INFINITY; l_i[mf][r] = 0.f; }

    for (int kc = 0; kc < 32; ++kc) {
        // ---- stage K chunk [64 keys][64 d] and Vt chunk [64 d][64 keys] ----
        // LDS rows are 128B; logical byte b of row stored at (b ^ ((row&7)<<4)).
#pragma unroll
        for (int i = 0; i < 2; ++i) {
            const int lb = (wid * 2 + i) * 1024;
            const int row = (lb >> 7) + (lane >> 3);
            const int inrow = (lane & 7) * 16;
            const int srcin = inrow ^ ((row & 7) << 4);
            const char* gk = Kb + (size_t)(kc * 64 + row) * 128 + srcin;
            __builtin_amdgcn_global_load_lds(AS1C(gk), AS3((char*)Ks + lb), 16, 0, 0);
            const char* gv = Vtb + (size_t)row * 4096 + kc * 128 + srcin;
            __builtin_amdgcn_global_load_lds(AS1C(gv), AS3((char*)Vs + lb), 16, 0, 0);
        }
        __syncthreads();

        // ---- S = Q K^T ----
        f32x4 sacc[2][4] = {};
#pragma unroll
        for (int kf = 0; kf < 2; ++kf) {
            s16x8 bk[4];
#pragma unroll
            for (int nf = 0; nf < 4; ++nf) {
                const int key = nf * 16 + (lane & 15);
                bk[nf] = *(const s16x8*)((const char*)Ks + key * 128 +
                                         (((kf * 32 + (lane >> 4) * 8) * 2) ^ ((key & 7) << 4)));
            }
#pragma unroll
            for (int mf = 0; mf < 2; ++mf)
#pragma unroll
                for (int nf = 0; nf < 4; ++nf)
                    sacc[mf][nf] = __builtin_amdgcn_mfma_f32_16x16x32_bf16(aq[mf][kf], bk[nf], sacc[mf][nf], 0, 0, 0);
        }

        // ---- online softmax (per row; cols live in 16-lane groups) ----
#pragma unroll
        for (int mf = 0; mf < 2; ++mf) {
#pragma unroll
            for (int r = 0; r < 4; ++r) {
                float v = fmaxf(fmaxf(sacc[mf][0][r], sacc[mf][1][r]),
                                fmaxf(sacc[mf][2][r], sacc[mf][3][r]));
#pragma unroll
                for (int mk = 1; mk < 16; mk <<= 1) v = fmaxf(v, __shfl_xor(v, mk, 64));
                v *= SCALE;
                const float mo = m_i[mf][r];
                const float mn = fmaxf(mo, v);
                const float fac = __expf(mo - mn);
                m_i[mf][r] = mn;
#pragma unroll
                for (int df = 0; df < 4; ++df) o_acc[mf][df][r] *= fac;

                const int prow = mf * 16 + (lane >> 4) * 4 + r;
                char* pbase = PsW + prow * 128;
                float rs = 0.f;
#pragma unroll
                for (int nf = 0; nf < 4; ++nf) {
                    const float p = __expf(sacc[mf][nf][r] * SCALE - mn);
                    rs += p;
                    const int cb = (nf * 16 + (lane & 15)) * 2;
                    *(unsigned short*)(pbase + (cb ^ ((prow & 7) << 4))) = f2bf(p);
                }
#pragma unroll
                for (int mk = 1; mk < 16; mk <<= 1) rs += __shfl_xor(rs, mk, 64);
                l_i[mf][r] = l_i[mf][r] * fac + rs;
            }
        }

        // ---- O += P @ V ----
        s16x8 pa[2][2];
#pragma unroll
        for (int mf = 0; mf < 2; ++mf)
#pragma unroll
            for (int kf = 0; kf < 2; ++kf) {
                const int prow = mf * 16 + (lane & 15);
                pa[mf][kf] = *(const s16x8*)(PsW + prow * 128 +
                                             (((kf * 32 + (lane >> 4) * 8) * 2) ^ ((prow & 7) << 4)));
            }
#pragma unroll
        for (int kf = 0; kf < 2; ++kf) {
            s16x8 bv[4];
#pragma unroll
            for (int df = 0; df < 4; ++df) {
                const int drow = df * 16 + (lane & 15);
                bv[df] = *(const s16x8*)((const char*)Vs + drow * 128 +
                                         (((kf * 32 + (lane >> 4) * 8) * 2) ^ ((drow & 7) << 4)));
            }
#pragma unroll
            for (int mf = 0; mf < 2; ++mf)
#pragma unroll
                for (int df = 0; df < 4; ++df)
                    o_acc[mf][df] = __builtin_amdgcn_mfma_f32_16x16x32_bf16(pa[mf][kf], bv[df], o_acc[mf][df], 0, 0, 0);
        }
        __syncthreads();
    }

    // ---- epilogue: O[b][s][h*64+d] = o_acc / l ----
#pragma unroll
    for (int mf = 0; mf < 2; ++mf) {
        float inv[4];
#pragma unroll
        for (int r = 0; r < 4; ++r) inv[r] = 1.f / l_i[mf][r];
#pragma unroll
        for (int df = 0; df < 4; ++df) {
#pragma unroll
            for (int r = 0; r < 4; ++r) {
                const int srow = q0 + mf * 16 + (lane >> 4) * 4 + r;
                const int dcol = df * 16 + (lane & 15);
                O[(size_t)(b * 2048 + srow) * 1024 + h * 64 + dcol] = f2bf(o_acc[mf][df][r] * inv[r]);
            }
        }
    }
}

// ---------------------------------------------------------------------------
extern "C" void kernel_launch(void* const* d_in, const int* in_sizes, int n_in,
                              void* d_out, int out_size, void* d_ws, size_t ws_size,
                              hipStream_t stream) {
    const float* query = (const float*)d_in[0];   // [2,2048,1024]
    const float* w_qkv = (const float*)d_in[1];   // [3072,1024]
    const float* b_qkv = (const float*)d_in[2];   // [3072]
    const float* w_out = (const float*)d_in[3];   // [1024,1024]
    const float* b_out = (const float*)d_in[4];   // [1024]
    float* out = (float*)d_out;                   // [2,2048,1024] fp32

    unsigned short* ws = (unsigned short*)d_ws;
    unsigned short* Xbf    = ws;                       // 4096*1024
    unsigned short* Wqkvbf = Xbf + 4096 * 1024;        // 3072*1024
    unsigned short* Woutbf = Wqkvbf + 3072 * 1024;     // 1024*1024
    unsigned short* Qw     = Woutbf + 1024 * 1024;     // 32*2048*64
    unsigned short* Kw     = Qw + 32 * 2048 * 64;
    unsigned short* Vtw    = Kw + 32 * 2048 * 64;
    unsigned short* Obf    = Vtw + 32 * 2048 * 64;     // 4096*1024

    cvt_bf16<<<(4096 * 1024 / 4 + 255) / 256, 256, 0, stream>>>(query, Xbf, 4096 * 1024 / 4);
    cvt_bf16<<<(3072 * 1024 / 4 + 255) / 256, 256, 0, stream>>>(w_qkv, Wqkvbf, 3072 * 1024 / 4);
    cvt_bf16<<<(1024 * 1024 / 4 + 255) / 256, 256, 0, stream>>>(w_out, Woutbf, 1024 * 1024 / 4);

    gemm_bt<0><<<dim3(3072 / 128, 4096 / 128), 256, 0, stream>>>(
        Xbf, Wqkvbf, b_qkv, nullptr, Qw, Kw, Vtw, 4096, 3072, 1024);

    attn_fwd<<<dim3(16, 32), 256, 0, stream>>>(Qw, Kw, Vtw, Obf);

    gemm_bt<1><<<dim3(1024 / 128, 4096 / 128), 256, 0, stream>>>(
        Obf, Woutbf, b_out, out, nullptr, nullptr, nullptr, 4096, 1024, 1024);
}

// Round 2
// 187.665 us; speedup vs baseline: 1.0230x; 1.0230x over previous
//
#include <hip/hip_runtime.h>
#include <hip/hip_bf16.h>
#include <cstdint>
#include <cstddef>

// ---------------------------------------------------------------------------
// MultiHeadAttention: B=2, S=2048, E=1024, H=16, D=64. fp32 in/out.
// Pipeline: cvt(f32->bf16) -> QKV GEMM (scatter Q*scale,K,V^T bf16) ->
//           flash attn (base-2 softmax, defer-max) -> out GEMM (fp32 + bias).
// ---------------------------------------------------------------------------

typedef float f32x4 __attribute__((ext_vector_type(4)));
typedef short s16x8 __attribute__((ext_vector_type(8)));

#define AS1C(p) ((const __attribute__((address_space(1))) void*)(p))
#define AS3(p)  ((__attribute__((address_space(3))) void*)(p))

__device__ __forceinline__ unsigned short f2bf(float f) {
    union { float f; unsigned u; } v; v.f = f;
    return (unsigned short)((v.u + 0x7FFFu + ((v.u >> 16) & 1u)) >> 16);
}

__device__ __forceinline__ float fast_exp2(float x) {
#if __has_builtin(__builtin_amdgcn_exp2f)
    return __builtin_amdgcn_exp2f(x);
#else
    return exp2f(x);
#endif
}

// ---------------------------------------------------------------------------
// fp32 -> bf16 convert (vectorized, n divisible by 4)
// ---------------------------------------------------------------------------
__global__ void cvt_bf16(const float* __restrict__ src,
                         unsigned short* __restrict__ dst, int n4) {
    int i = blockIdx.x * blockDim.x + threadIdx.x;
    if (i >= n4) return;
    float4 f = reinterpret_cast<const float4*>(src)[i];
    ushort4 o;
    o.x = f2bf(f.x); o.y = f2bf(f.y); o.z = f2bf(f.z); o.w = f2bf(f.w);
    reinterpret_cast<ushort4*>(dst)[i] = o;
}

// ---------------------------------------------------------------------------
// GEMM: C[M,N] = A[M,K] @ B[N,K]^T + bias[N]
// MODE 0: scatter bf16 into Q*QSCALE [b,h,s,d], K[b,h,s,d], Vt[b,h,d,s]
// MODE 1: fp32 store to Cf[M,N]
// ---------------------------------------------------------------------------
// softmax scale folded into Q, in base-2 domain: 1/sqrt(64) * log2(e)
#define QSCALE_L2E (0.125f * 1.44269504088896f)

template <int MODE>
__global__ __launch_bounds__(256, 2)
void gemm_bt(const unsigned short* __restrict__ A,
             const unsigned short* __restrict__ B,
             const float* __restrict__ bias,
             float* __restrict__ Cf,
             unsigned short* __restrict__ Qw,
             unsigned short* __restrict__ Kw,
             unsigned short* __restrict__ Vtw,
             int M, int N, int K) {
    constexpr int BK = 32;
    __shared__ unsigned short As[128 * BK];
    __shared__ unsigned short Bs[128 * BK];

    const int tid = threadIdx.x;
    const int wid = tid >> 6, lane = tid & 63;
    const int brow = blockIdx.y * 128, bcol = blockIdx.x * 128;
    const int wr = wid >> 1, wc = wid & 1;

    f32x4 acc[4][4] = {};

    const int kIters = K / BK;
    for (int kt = 0; kt < kIters; ++kt) {
#pragma unroll
        for (int i = 0; i < 2; ++i) {
            const int lb = (wid * 2 + i) * 1024;        // wave-uniform LDS byte base
            const int row = (lb >> 6) + (lane >> 2);    // 64B per row
            const int inrow = (lane & 3) * 16;
            const char* ga = (const char*)A + ((size_t)(brow + row) * K + kt * BK) * 2 + inrow;
            __builtin_amdgcn_global_load_lds(AS1C(ga), AS3((char*)As + lb), 16, 0, 0);
            const char* gb = (const char*)B + ((size_t)(bcol + row) * K + kt * BK) * 2 + inrow;
            __builtin_amdgcn_global_load_lds(AS1C(gb), AS3((char*)Bs + lb), 16, 0, 0);
        }
        __syncthreads();

        s16x8 af[4], bfr[4];
#pragma unroll
        for (int f = 0; f < 4; ++f) {
            af[f]  = *(const s16x8*)((const char*)As + (wr * 64 + f * 16 + (lane & 15)) * 64 + (lane >> 4) * 16);
            bfr[f] = *(const s16x8*)((const char*)Bs + (wc * 64 + f * 16 + (lane & 15)) * 64 + (lane >> 4) * 16);
        }
#pragma unroll
        for (int mf = 0; mf < 4; ++mf)
#pragma unroll
            for (int nf = 0; nf < 4; ++nf)
                acc[mf][nf] = __builtin_amdgcn_mfma_f32_16x16x32_bf16(af[mf], bfr[nf], acc[mf][nf], 0, 0, 0);
        __syncthreads();
    }

    // ---- epilogue ----
    float bv[4];
#pragma unroll
    for (int nf = 0; nf < 4; ++nf) bv[nf] = bias[bcol + wc * 64 + nf * 16 + (lane & 15)];

#pragma unroll
    for (int mf = 0; mf < 4; ++mf) {
#pragma unroll
        for (int r = 0; r < 4; ++r) {
            const int row = brow + wr * 64 + mf * 16 + (lane >> 4) * 4 + r;
#pragma unroll
            for (int nf = 0; nf < 4; ++nf) {
                const int col = bcol + wc * 64 + nf * 16 + (lane & 15);
                float v = acc[mf][nf][r] + bv[nf];
                if constexpr (MODE == 0) {
                    const int which = col >> 10, e = col & 1023;
                    const int h = e >> 6, d = e & 63;
                    const int b = row >> 11, s = row & 2047;
                    const size_t bh = (size_t)(b * 16 + h);
                    if (which == 0)      Qw[(bh * 2048 + s) * 64 + d] = f2bf(v * QSCALE_L2E);
                    else if (which == 1) Kw[(bh * 2048 + s) * 64 + d] = f2bf(v);
                    else                 Vtw[(bh * 64 + d) * 2048 + s] = f2bf(v);
                } else {
                    Cf[(size_t)row * N + col] = v;
                }
            }
        }
    }
}

// ---------------------------------------------------------------------------
// Flash attention fwd. Grid: (qtile=32, bh=32) = 1024 blocks. Block: 256
// threads (4 waves), each wave owns 16 q-rows. K/V chunks of 64 keys staged
// in LDS (XOR-swizzled via pre-swizzled global source). Base-2 online
// softmax with defer-max (THR=8 -> P bounded by 2^8, bf16-safe).
// ---------------------------------------------------------------------------
__global__ __launch_bounds__(256, 4)
void attn_fwd(const unsigned short* __restrict__ Q,   // [32][2048][64] (pre-scaled)
              const unsigned short* __restrict__ Kk,  // [32][2048][64]
              const unsigned short* __restrict__ Vt,  // [32][64][2048]
              unsigned short* __restrict__ O) {       // [4096][1024] (B,S,E)
    __shared__ unsigned short Ks[64 * 64];       // [key][d] swizzled, 8KB
    __shared__ unsigned short Vs[64 * 64];       // [d][key] swizzled, 8KB
    __shared__ unsigned short Ps[4 * 16 * 64];   // per-wave P [16][64] swizzled, 8KB

    const int tid = threadIdx.x;
    const int wid = tid >> 6, lane = tid & 63;
    const int bh = blockIdx.y;
    const int b = bh >> 4, h = bh & 15;
    const int q0 = blockIdx.x * 64 + wid * 16;   // first q row for this wave

    const char* Qb  = (const char*)(Q  + (size_t)bh * 2048 * 64);
    const char* Kb  = (const char*)(Kk + (size_t)bh * 2048 * 64);
    const char* Vtb = (const char*)(Vt + (size_t)bh * 64 * 2048);
    char* PsW = (char*)Ps + wid * 2048;          // this wave's P region (16*64*2B)

    // Q fragments: rows q0+(lane&15), k = kf*32+(lane>>4)*8
    s16x8 aq[2];
#pragma unroll
    for (int kf = 0; kf < 2; ++kf)
        aq[kf] = *(const s16x8*)(Qb + (size_t)(q0 + (lane & 15)) * 128 +
                                 (kf * 32 + (lane >> 4) * 8) * 2);

    float m_i[4], l_i[4];
    f32x4 o_acc[4] = {};
#pragma unroll
    for (int r = 0; r < 4; ++r) { m_i[r] = -INFINITY; l_i[r] = 0.f; }

    for (int kc = 0; kc < 32; ++kc) {
        // ---- stage K chunk [64 keys][64 d] and Vt chunk [64 d][64 keys] ----
        // LDS rows are 128B; logical byte cb of row stored at (cb ^ ((row&7)<<4)).
#pragma unroll
        for (int i = 0; i < 2; ++i) {
            const int lb = (wid * 2 + i) * 1024;
            const int row = (lb >> 7) + (lane >> 3);
            const int inrow = (lane & 7) * 16;
            const int srcin = inrow ^ ((row & 7) << 4);
            const char* gk = Kb + (size_t)(kc * 64 + row) * 128 + srcin;
            __builtin_amdgcn_global_load_lds(AS1C(gk), AS3((char*)Ks + lb), 16, 0, 0);
            const char* gv = Vtb + (size_t)row * 4096 + kc * 128 + srcin;
            __builtin_amdgcn_global_load_lds(AS1C(gv), AS3((char*)Vs + lb), 16, 0, 0);
        }
        __syncthreads();

        // ---- S = Q K^T (scores already in base-2 log-domain scale) ----
        f32x4 sacc[4] = {};
#pragma unroll
        for (int kf = 0; kf < 2; ++kf) {
            s16x8 bk[4];
#pragma unroll
            for (int nf = 0; nf < 4; ++nf) {
                const int key = nf * 16 + (lane & 15);
                bk[nf] = *(const s16x8*)((const char*)Ks + key * 128 +
                                         (((kf * 32 + (lane >> 4) * 8) * 2) ^ ((key & 7) << 4)));
            }
#pragma unroll
            for (int nf = 0; nf < 4; ++nf)
                sacc[nf] = __builtin_amdgcn_mfma_f32_16x16x32_bf16(aq[kf], bk[nf], sacc[nf], 0, 0, 0);
        }

        // ---- online softmax, base-2 domain, defer-max ----
        float vr[4];
#pragma unroll
        for (int r = 0; r < 4; ++r) {
            float v = fmaxf(fmaxf(sacc[0][r], sacc[1][r]),
                            fmaxf(sacc[2][r], sacc[3][r]));
#pragma unroll
            for (int mk = 1; mk < 16; mk <<= 1) v = fmaxf(v, __shfl_xor(v, mk, 64));
            vr[r] = v;
        }
        bool upd = false;
#pragma unroll
        for (int r = 0; r < 4; ++r) upd |= (vr[r] > m_i[r] + 8.0f);
        if (__any(upd)) {
#pragma unroll
            for (int r = 0; r < 4; ++r) {
                const float mn = fmaxf(m_i[r], vr[r]);
                const float fac = fast_exp2(m_i[r] - mn);
                l_i[r] *= fac;
#pragma unroll
                for (int df = 0; df < 4; ++df) o_acc[df][r] *= fac;
                m_i[r] = mn;
            }
        }
#pragma unroll
        for (int r = 0; r < 4; ++r) {
            const int prow = (lane >> 4) * 4 + r;
            char* pbase = PsW + prow * 128;
            float rs = 0.f;
#pragma unroll
            for (int nf = 0; nf < 4; ++nf) {
                const float p = fast_exp2(sacc[nf][r] - m_i[r]);
                rs += p;
                const int cb = (nf * 16 + (lane & 15)) * 2;
                *(unsigned short*)(pbase + (cb ^ ((prow & 7) << 4))) = f2bf(p);
            }
#pragma unroll
            for (int mk = 1; mk < 16; mk <<= 1) rs += __shfl_xor(rs, mk, 64);
            l_i[r] += rs;
        }

        // ---- O += P @ V ----
        s16x8 pa[2];
#pragma unroll
        for (int kf = 0; kf < 2; ++kf) {
            const int prow = lane & 15;
            pa[kf] = *(const s16x8*)(PsW + prow * 128 +
                                     (((kf * 32 + (lane >> 4) * 8) * 2) ^ ((prow & 7) << 4)));
        }
#pragma unroll
        for (int kf = 0; kf < 2; ++kf) {
            s16x8 bv[4];
#pragma unroll
            for (int df = 0; df < 4; ++df) {
                const int drow = df * 16 + (lane & 15);
                bv[df] = *(const s16x8*)((const char*)Vs + drow * 128 +
                                         (((kf * 32 + (lane >> 4) * 8) * 2) ^ ((drow & 7) << 4)));
            }
#pragma unroll
            for (int df = 0; df < 4; ++df)
                o_acc[df] = __builtin_amdgcn_mfma_f32_16x16x32_bf16(pa[kf], bv[df], o_acc[df], 0, 0, 0);
        }
        __syncthreads();
    }

    // ---- epilogue: O[b][s][h*64+d] = o_acc / l ----
    float inv[4];
#pragma unroll
    for (int r = 0; r < 4; ++r) inv[r] = 1.f / l_i[r];
#pragma unroll
    for (int df = 0; df < 4; ++df) {
#pragma unroll
        for (int r = 0; r < 4; ++r) {
            const int srow = q0 + (lane >> 4) * 4 + r;
            const int dcol = df * 16 + (lane & 15);
            O[(size_t)(b * 2048 + srow) * 1024 + h * 64 + dcol] = f2bf(o_acc[df][r] * inv[r]);
        }
    }
}

// ---------------------------------------------------------------------------
extern "C" void kernel_launch(void* const* d_in, const int* in_sizes, int n_in,
                              void* d_out, int out_size, void* d_ws, size_t ws_size,
                              hipStream_t stream) {
    const float* query = (const float*)d_in[0];   // [2,2048,1024]
    const float* w_qkv = (const float*)d_in[1];   // [3072,1024]
    const float* b_qkv = (const float*)d_in[2];   // [3072]
    const float* w_out = (const float*)d_in[3];   // [1024,1024]
    const float* b_out = (const float*)d_in[4];   // [1024]
    float* out = (float*)d_out;                   // [2,2048,1024] fp32

    unsigned short* ws = (unsigned short*)d_ws;
    unsigned short* Xbf    = ws;                       // 4096*1024
    unsigned short* Wqkvbf = Xbf + 4096 * 1024;        // 3072*1024
    unsigned short* Woutbf = Wqkvbf + 3072 * 1024;     // 1024*1024
    unsigned short* Qw     = Woutbf + 1024 * 1024;     // 32*2048*64
    unsigned short* Kw     = Qw + 32 * 2048 * 64;
    unsigned short* Vtw    = Kw + 32 * 2048 * 64;
    unsigned short* Obf    = Vtw + 32 * 2048 * 64;     // 4096*1024

    cvt_bf16<<<(4096 * 1024 / 4 + 255) / 256, 256, 0, stream>>>(query, Xbf, 4096 * 1024 / 4);
    cvt_bf16<<<(3072 * 1024 / 4 + 255) / 256, 256, 0, stream>>>(w_qkv, Wqkvbf, 3072 * 1024 / 4);
    cvt_bf16<<<(1024 * 1024 / 4 + 255) / 256, 256, 0, stream>>>(w_out, Woutbf, 1024 * 1024 / 4);

    gemm_bt<0><<<dim3(3072 / 128, 4096 / 128), 256, 0, stream>>>(
        Xbf, Wqkvbf, b_qkv, nullptr, Qw, Kw, Vtw, 4096, 3072, 1024);

    attn_fwd<<<dim3(32, 32), 256, 0, stream>>>(Qw, Kw, Vtw, Obf);

    gemm_bt<1><<<dim3(1024 / 128, 4096 / 128), 256, 0, stream>>>(
        Obf, Woutbf, b_out, out, nullptr, nullptr, nullptr, 4096, 1024, 1024);
}

// Round 3
// 147.709 us; speedup vs baseline: 1.2997x; 1.2705x over previous
//
#include <hip/hip_runtime.h>
#include <hip/hip_bf16.h>
#include <cstdint>
#include <cstddef>

// ---------------------------------------------------------------------------
// MultiHeadAttention: B=2, S=2048, E=1024, H=16, D=64. fp32 in/out.
// Pipeline: cvt(f32->bf16) -> QKV GEMM (scatter Q*scale,K,V^T bf16) ->
//           flash attn (base-2, STATIC max, l via ones-MFMA, dbuf K/V) ->
//           out GEMM (fp32 + bias).
// ---------------------------------------------------------------------------

typedef float f32x4 __attribute__((ext_vector_type(4)));
typedef short s16x8 __attribute__((ext_vector_type(8)));

#define AS1C(p) ((const __attribute__((address_space(1))) void*)(p))
#define AS3(p)  ((__attribute__((address_space(3))) void*)(p))

__device__ __forceinline__ unsigned short f2bf(float f) {
    union { float f; unsigned u; } v; v.f = f;
    return (unsigned short)((v.u + 0x7FFFu + ((v.u >> 16) & 1u)) >> 16);
}

__device__ __forceinline__ float fast_exp2(float x) {
#if __has_builtin(__builtin_amdgcn_exp2f)
    return __builtin_amdgcn_exp2f(x);
#else
    return exp2f(x);
#endif
}

// ---------------------------------------------------------------------------
// fp32 -> bf16 convert (vectorized, n divisible by 4)
// ---------------------------------------------------------------------------
__global__ void cvt_bf16(const float* __restrict__ src,
                         unsigned short* __restrict__ dst, int n4) {
    int i = blockIdx.x * blockDim.x + threadIdx.x;
    if (i >= n4) return;
    float4 f = reinterpret_cast<const float4*>(src)[i];
    ushort4 o;
    o.x = f2bf(f.x); o.y = f2bf(f.y); o.z = f2bf(f.z); o.w = f2bf(f.w);
    reinterpret_cast<ushort4*>(dst)[i] = o;
}

// ---------------------------------------------------------------------------
// GEMM: C[M,N] = A[M,K] @ B[N,K]^T + bias[N]
// MODE 0: scatter bf16 into Q*QSCALE [b,h,s,d], K[b,h,s,d], Vt[b,h,d,s]
// MODE 1: fp32 store to Cf[M,N]
// ---------------------------------------------------------------------------
// softmax scale folded into Q, in base-2 domain: 1/sqrt(64) * log2(e)
#define QSCALE_L2E (0.125f * 1.44269504088896f)

template <int MODE>
__global__ __launch_bounds__(256, 2)
void gemm_bt(const unsigned short* __restrict__ A,
             const unsigned short* __restrict__ B,
             const float* __restrict__ bias,
             float* __restrict__ Cf,
             unsigned short* __restrict__ Qw,
             unsigned short* __restrict__ Kw,
             unsigned short* __restrict__ Vtw,
             int M, int N, int K) {
    constexpr int BK = 32;
    __shared__ unsigned short As[128 * BK];
    __shared__ unsigned short Bs[128 * BK];

    const int tid = threadIdx.x;
    const int wid = tid >> 6, lane = tid & 63;
    const int brow = blockIdx.y * 128, bcol = blockIdx.x * 128;
    const int wr = wid >> 1, wc = wid & 1;

    f32x4 acc[4][4] = {};

    const int kIters = K / BK;
    for (int kt = 0; kt < kIters; ++kt) {
#pragma unroll
        for (int i = 0; i < 2; ++i) {
            const int lb = (wid * 2 + i) * 1024;        // wave-uniform LDS byte base
            const int row = (lb >> 6) + (lane >> 2);    // 64B per row
            const int inrow = (lane & 3) * 16;
            const char* ga = (const char*)A + ((size_t)(brow + row) * K + kt * BK) * 2 + inrow;
            __builtin_amdgcn_global_load_lds(AS1C(ga), AS3((char*)As + lb), 16, 0, 0);
            const char* gb = (const char*)B + ((size_t)(bcol + row) * K + kt * BK) * 2 + inrow;
            __builtin_amdgcn_global_load_lds(AS1C(gb), AS3((char*)Bs + lb), 16, 0, 0);
        }
        __syncthreads();

        s16x8 af[4], bfr[4];
#pragma unroll
        for (int f = 0; f < 4; ++f) {
            af[f]  = *(const s16x8*)((const char*)As + (wr * 64 + f * 16 + (lane & 15)) * 64 + (lane >> 4) * 16);
            bfr[f] = *(const s16x8*)((const char*)Bs + (wc * 64 + f * 16 + (lane & 15)) * 64 + (lane >> 4) * 16);
        }
#pragma unroll
        for (int mf = 0; mf < 4; ++mf)
#pragma unroll
            for (int nf = 0; nf < 4; ++nf)
                acc[mf][nf] = __builtin_amdgcn_mfma_f32_16x16x32_bf16(af[mf], bfr[nf], acc[mf][nf], 0, 0, 0);
        __syncthreads();
    }

    // ---- epilogue ----
    float bv[4];
#pragma unroll
    for (int nf = 0; nf < 4; ++nf) bv[nf] = bias[bcol + wc * 64 + nf * 16 + (lane & 15)];

#pragma unroll
    for (int mf = 0; mf < 4; ++mf) {
#pragma unroll
        for (int r = 0; r < 4; ++r) {
            const int row = brow + wr * 64 + mf * 16 + (lane >> 4) * 4 + r;
#pragma unroll
            for (int nf = 0; nf < 4; ++nf) {
                const int col = bcol + wc * 64 + nf * 16 + (lane & 15);
                float v = acc[mf][nf][r] + bv[nf];
                if constexpr (MODE == 0) {
                    const int which = col >> 10, e = col & 1023;
                    const int h = e >> 6, d = e & 63;
                    const int b = row >> 11, s = row & 2047;
                    const size_t bh = (size_t)(b * 16 + h);
                    if (which == 0)      Qw[(bh * 2048 + s) * 64 + d] = f2bf(v * QSCALE_L2E);
                    else if (which == 1) Kw[(bh * 2048 + s) * 64 + d] = f2bf(v);
                    else                 Vtw[(bh * 64 + d) * 2048 + s] = f2bf(v);
                } else {
                    Cf[(size_t)row * N + col] = v;
                }
            }
        }
    }
}

// ---------------------------------------------------------------------------
// Flash attention fwd. Grid: (qtile=32, bh=32) = 1024 blocks. Block: 256
// threads (4 waves), each wave owns 16 q-rows. K/V chunks of 64 keys,
// double-buffered in LDS (XOR-swizzled via pre-swizzled global source).
// Static-max base-2 softmax: P = exp2(q.k*scale_l2e - 16); the -16 is the
// MFMA C-init. Row sums l computed by an extra MFMA against all-ones B.
// One barrier per chunk.
// ---------------------------------------------------------------------------
__global__ __launch_bounds__(256, 4)
void attn_fwd(const unsigned short* __restrict__ Q,   // [32][2048][64] (pre-scaled)
              const unsigned short* __restrict__ Kk,  // [32][2048][64]
              const unsigned short* __restrict__ Vt,  // [32][64][2048]
              unsigned short* __restrict__ O) {       // [4096][1024] (B,S,E)
    __shared__ unsigned short Ks[2][64 * 64];    // [key][d] swizzled, 2x8KB
    __shared__ unsigned short Vs[2][64 * 64];    // [d][key] swizzled, 2x8KB
    __shared__ unsigned short Ps[4 * 16 * 64];   // per-wave P [16][64] swizzled, 8KB

    const int tid = threadIdx.x;
    const int wid = tid >> 6, lane = tid & 63;
    const int bh = blockIdx.y;
    const int b = bh >> 4, h = bh & 15;
    const int q0 = blockIdx.x * 64 + wid * 16;   // first q row for this wave

    const char* Qb  = (const char*)(Q  + (size_t)bh * 2048 * 64);
    const char* Kb  = (const char*)(Kk + (size_t)bh * 2048 * 64);
    const char* Vtb = (const char*)(Vt + (size_t)bh * 64 * 2048);
    char* PsW = (char*)Ps + wid * 2048;          // this wave's P region (16*64*2B)

    // Q fragments: rows q0+(lane&15), k = kf*32+(lane>>4)*8
    s16x8 aq[2];
#pragma unroll
    for (int kf = 0; kf < 2; ++kf)
        aq[kf] = *(const s16x8*)(Qb + (size_t)(q0 + (lane & 15)) * 128 +
                                 (kf * 32 + (lane >> 4) * 8) * 2);

    f32x4 o_acc[4] = {};
    f32x4 l_acc = {};
    s16x8 ones;
#pragma unroll
    for (int j = 0; j < 8; ++j) ones[j] = (short)0x3F80;  // bf16 1.0

    // stage K chunk [64 keys][64 d] and Vt chunk [64 d][64 keys] into buf.
    // LDS rows are 128B; logical byte cb of row stored at (cb ^ ((row&7)<<4)).
    auto stage = [&](int kc, int buf) {
#pragma unroll
        for (int i = 0; i < 2; ++i) {
            const int lb = (wid * 2 + i) * 1024;
            const int row = (lb >> 7) + (lane >> 3);
            const int inrow = (lane & 7) * 16;
            const int srcin = inrow ^ ((row & 7) << 4);
            const char* gk = Kb + (size_t)(kc * 64 + row) * 128 + srcin;
            __builtin_amdgcn_global_load_lds(AS1C(gk), AS3((char*)Ks[buf] + lb), 16, 0, 0);
            const char* gv = Vtb + (size_t)row * 4096 + kc * 128 + srcin;
            __builtin_amdgcn_global_load_lds(AS1C(gv), AS3((char*)Vs[buf] + lb), 16, 0, 0);
        }
    };

    stage(0, 0);
    __syncthreads();

    for (int kc = 0; kc < 32; ++kc) {
        const int cur = kc & 1;
        if (kc < 31) stage(kc + 1, cur ^ 1);   // prefetch next chunk

        // ---- S = Q K^T - 16 (C-init does the subtract) ----
        f32x4 sacc[4];
#pragma unroll
        for (int nf = 0; nf < 4; ++nf) sacc[nf] = f32x4{-16.f, -16.f, -16.f, -16.f};
#pragma unroll
        for (int kf = 0; kf < 2; ++kf) {
            s16x8 bk[4];
#pragma unroll
            for (int nf = 0; nf < 4; ++nf) {
                const int key = nf * 16 + (lane & 15);
                bk[nf] = *(const s16x8*)((const char*)Ks[cur] + key * 128 +
                                         (((kf * 32 + (lane >> 4) * 8) * 2) ^ ((key & 7) << 4)));
            }
#pragma unroll
            for (int nf = 0; nf < 4; ++nf)
                sacc[nf] = __builtin_amdgcn_mfma_f32_16x16x32_bf16(aq[kf], bk[nf], sacc[nf], 0, 0, 0);
        }

        // ---- P = exp2(S), store to wave-private LDS (swizzled) ----
#pragma unroll
        for (int r = 0; r < 4; ++r) {
            const int prow = (lane >> 4) * 4 + r;
            char* pbase = PsW + prow * 128;
#pragma unroll
            for (int nf = 0; nf < 4; ++nf) {
                const float p = fast_exp2(sacc[nf][r]);
                const int cb = (nf * 16 + (lane & 15)) * 2;
                *(unsigned short*)(pbase + (cb ^ ((prow & 7) << 4))) = f2bf(p);
            }
        }

        // ---- l += P @ 1 ; O += P @ V ----
        s16x8 pa[2];
#pragma unroll
        for (int kf = 0; kf < 2; ++kf) {
            const int prow = lane & 15;
            pa[kf] = *(const s16x8*)(PsW + prow * 128 +
                                     (((kf * 32 + (lane >> 4) * 8) * 2) ^ ((prow & 7) << 4)));
        }
#pragma unroll
        for (int kf = 0; kf < 2; ++kf) {
            l_acc = __builtin_amdgcn_mfma_f32_16x16x32_bf16(pa[kf], ones, l_acc, 0, 0, 0);
            s16x8 bv[4];
#pragma unroll
            for (int df = 0; df < 4; ++df) {
                const int drow = df * 16 + (lane & 15);
                bv[df] = *(const s16x8*)((const char*)Vs[cur] + drow * 128 +
                                         (((kf * 32 + (lane >> 4) * 8) * 2) ^ ((drow & 7) << 4)));
            }
#pragma unroll
            for (int df = 0; df < 4; ++df)
                o_acc[df] = __builtin_amdgcn_mfma_f32_16x16x32_bf16(pa[kf], bv[df], o_acc[df], 0, 0, 0);
        }
        __syncthreads();   // all waves done reading bufs; next-chunk loads drained here
    }

    // ---- epilogue: O[b][s][h*64+d] = o_acc / l ----
    float inv[4];
#pragma unroll
    for (int r = 0; r < 4; ++r) inv[r] = 1.f / l_acc[r];
#pragma unroll
    for (int df = 0; df < 4; ++df) {
#pragma unroll
        for (int r = 0; r < 4; ++r) {
            const int srow = q0 + (lane >> 4) * 4 + r;
            const int dcol = df * 16 + (lane & 15);
            O[(size_t)(b * 2048 + srow) * 1024 + h * 64 + dcol] = f2bf(o_acc[df][r] * inv[r]);
        }
    }
}

// ---------------------------------------------------------------------------
extern "C" void kernel_launch(void* const* d_in, const int* in_sizes, int n_in,
                              void* d_out, int out_size, void* d_ws, size_t ws_size,
                              hipStream_t stream) {
    const float* query = (const float*)d_in[0];   // [2,2048,1024]
    const float* w_qkv = (const float*)d_in[1];   // [3072,1024]
    const float* b_qkv = (const float*)d_in[2];   // [3072]
    const float* w_out = (const float*)d_in[3];   // [1024,1024]
    const float* b_out = (const float*)d_in[4];   // [1024]
    float* out = (float*)d_out;                   // [2,2048,1024] fp32

    unsigned short* ws = (unsigned short*)d_ws;
    unsigned short* Xbf    = ws;                       // 4096*1024
    unsigned short* Wqkvbf = Xbf + 4096 * 1024;        // 3072*1024
    unsigned short* Woutbf = Wqkvbf + 3072 * 1024;     // 1024*1024
    unsigned short* Qw     = Woutbf + 1024 * 1024;     // 32*2048*64
    unsigned short* Kw     = Qw + 32 * 2048 * 64;
    unsigned short* Vtw    = Kw + 32 * 2048 * 64;
    unsigned short* Obf    = Vtw + 32 * 2048 * 64;     // 4096*1024

    cvt_bf16<<<(4096 * 1024 / 4 + 255) / 256, 256, 0, stream>>>(query, Xbf, 4096 * 1024 / 4);
    cvt_bf16<<<(3072 * 1024 / 4 + 255) / 256, 256, 0, stream>>>(w_qkv, Wqkvbf, 3072 * 1024 / 4);
    cvt_bf16<<<(1024 * 1024 / 4 + 255) / 256, 256, 0, stream>>>(w_out, Woutbf, 1024 * 1024 / 4);

    gemm_bt<0><<<dim3(3072 / 128, 4096 / 128), 256, 0, stream>>>(
        Xbf, Wqkvbf, b_qkv, nullptr, Qw, Kw, Vtw, 4096, 3072, 1024);

    attn_fwd<<<dim3(32, 32), 256, 0, stream>>>(Qw, Kw, Vtw, Obf);

    gemm_bt<1><<<dim3(1024 / 128, 4096 / 128), 256, 0, stream>>>(
        Obf, Woutbf, b_out, out, nullptr, nullptr, nullptr, 4096, 1024, 1024);
}

// Round 4
// 132.385 us; speedup vs baseline: 1.4501x; 1.1158x over previous
//
#include <hip/hip_runtime.h>
#include <hip/hip_bf16.h>
#include <cstdint>
#include <cstddef>

// ---------------------------------------------------------------------------
// MultiHeadAttention: B=2, S=2048, E=1024, H=16, D=64. fp32 in/out.
// Pipeline: cvt(f32->bf16, fused) -> QKV GEMM (scatter Q*scale,K,V^T bf16) ->
//           flash attn (swapped QK^T, static max, cvt_pk P, XCD swizzle) ->
//           out GEMM (fp32 + bias).
// ---------------------------------------------------------------------------

typedef float f32x4 __attribute__((ext_vector_type(4)));
typedef short s16x8 __attribute__((ext_vector_type(8)));

#define AS1C(p) ((const __attribute__((address_space(1))) void*)(p))
#define AS3(p)  ((__attribute__((address_space(3))) void*)(p))

__device__ __forceinline__ unsigned short f2bf(float f) {
    union { float f; unsigned u; } v; v.f = f;
    return (unsigned short)((v.u + 0x7FFFu + ((v.u >> 16) & 1u)) >> 16);
}

__device__ __forceinline__ float fast_exp2(float x) {
#if __has_builtin(__builtin_amdgcn_exp2f)
    return __builtin_amdgcn_exp2f(x);
#else
    return exp2f(x);
#endif
}

// ---------------------------------------------------------------------------
// fused fp32 -> bf16 convert for 3 tensors (query, w_qkv, w_out)
// ---------------------------------------------------------------------------
__global__ void cvt_bf16_3(const float* __restrict__ a, const float* __restrict__ b,
                           const float* __restrict__ c,
                           unsigned short* __restrict__ oa, unsigned short* __restrict__ ob,
                           unsigned short* __restrict__ oc,
                           int na4, int nb4, int nc4) {
    int j = blockIdx.x * blockDim.x + threadIdx.x;
    const float* s; unsigned short* d;
    if (j < na4) { s = a; d = oa; }
    else {
        j -= na4;
        if (j < nb4) { s = b; d = ob; }
        else { j -= nb4; if (j >= nc4) return; s = c; d = oc; }
    }
    float4 f = reinterpret_cast<const float4*>(s)[j];
    ushort4 o;
    o.x = f2bf(f.x); o.y = f2bf(f.y); o.z = f2bf(f.z); o.w = f2bf(f.w);
    reinterpret_cast<ushort4*>(d)[j] = o;
}

// ---------------------------------------------------------------------------
// GEMM: C[M,N] = A[M,K] @ B[N,K]^T + bias[N]
// MODE 0: scatter bf16 into Q*QSCALE [b,h,s,d], K[b,h,s,d], Vt[b,h,d,s]
// MODE 1: fp32 store to Cf[M,N]
// ---------------------------------------------------------------------------
// softmax scale folded into Q, in base-2 domain: 1/sqrt(64) * log2(e)
#define QSCALE_L2E (0.125f * 1.44269504088896f)

template <int MODE>
__global__ __launch_bounds__(256, 2)
void gemm_bt(const unsigned short* __restrict__ A,
             const unsigned short* __restrict__ B,
             const float* __restrict__ bias,
             float* __restrict__ Cf,
             unsigned short* __restrict__ Qw,
             unsigned short* __restrict__ Kw,
             unsigned short* __restrict__ Vtw,
             int M, int N, int K) {
    constexpr int BK = 32;
    __shared__ unsigned short As[128 * BK];
    __shared__ unsigned short Bs[128 * BK];

    const int tid = threadIdx.x;
    const int wid = tid >> 6, lane = tid & 63;
    const int brow = blockIdx.y * 128, bcol = blockIdx.x * 128;
    const int wr = wid >> 1, wc = wid & 1;

    f32x4 acc[4][4] = {};

    const int kIters = K / BK;
    for (int kt = 0; kt < kIters; ++kt) {
#pragma unroll
        for (int i = 0; i < 2; ++i) {
            const int lb = (wid * 2 + i) * 1024;        // wave-uniform LDS byte base
            const int row = (lb >> 6) + (lane >> 2);    // 64B per row
            const int inrow = (lane & 3) * 16;
            const char* ga = (const char*)A + ((size_t)(brow + row) * K + kt * BK) * 2 + inrow;
            __builtin_amdgcn_global_load_lds(AS1C(ga), AS3((char*)As + lb), 16, 0, 0);
            const char* gb = (const char*)B + ((size_t)(bcol + row) * K + kt * BK) * 2 + inrow;
            __builtin_amdgcn_global_load_lds(AS1C(gb), AS3((char*)Bs + lb), 16, 0, 0);
        }
        __syncthreads();

        s16x8 af[4], bfr[4];
#pragma unroll
        for (int f = 0; f < 4; ++f) {
            af[f]  = *(const s16x8*)((const char*)As + (wr * 64 + f * 16 + (lane & 15)) * 64 + (lane >> 4) * 16);
            bfr[f] = *(const s16x8*)((const char*)Bs + (wc * 64 + f * 16 + (lane & 15)) * 64 + (lane >> 4) * 16);
        }
#pragma unroll
        for (int mf = 0; mf < 4; ++mf)
#pragma unroll
            for (int nf = 0; nf < 4; ++nf)
                acc[mf][nf] = __builtin_amdgcn_mfma_f32_16x16x32_bf16(af[mf], bfr[nf], acc[mf][nf], 0, 0, 0);
        __syncthreads();
    }

    // ---- epilogue ----
    float bv[4];
#pragma unroll
    for (int nf = 0; nf < 4; ++nf) bv[nf] = bias[bcol + wc * 64 + nf * 16 + (lane & 15)];

#pragma unroll
    for (int mf = 0; mf < 4; ++mf) {
#pragma unroll
        for (int r = 0; r < 4; ++r) {
            const int row = brow + wr * 64 + mf * 16 + (lane >> 4) * 4 + r;
#pragma unroll
            for (int nf = 0; nf < 4; ++nf) {
                const int col = bcol + wc * 64 + nf * 16 + (lane & 15);
                float v = acc[mf][nf][r] + bv[nf];
                if constexpr (MODE == 0) {
                    const int which = col >> 10, e = col & 1023;
                    const int h = e >> 6, d = e & 63;
                    const int b = row >> 11, s = row & 2047;
                    const size_t bh = (size_t)(b * 16 + h);
                    if (which == 0)      Qw[(bh * 2048 + s) * 64 + d] = f2bf(v * QSCALE_L2E);
                    else if (which == 1) Kw[(bh * 2048 + s) * 64 + d] = f2bf(v);
                    else                 Vtw[(bh * 64 + d) * 2048 + s] = f2bf(v);
                } else {
                    Cf[(size_t)row * N + col] = v;
                }
            }
        }
    }
}

// ---------------------------------------------------------------------------
// Flash attention fwd. 1D grid of 1024 blocks, XCD-chunked swizzle so each
// XCD owns 4 contiguous bh (2MB K/V -> L2-resident). Block: 256 threads
// (4 waves), each wave owns 16 q-rows. K/V chunks of 64 keys, double-buffered
// in LDS (XOR-swizzled via pre-swizzled global source).
// Swapped QK^T: sacc = mfma(K_frag, Q_frag) = S^T - 16, so key-adjacent P
// values are lane-local -> cvt_pk bf16 pack + ds_write_b64.
// Static-max base-2 softmax; row sums l via ones-MFMA. One barrier per chunk.
// ---------------------------------------------------------------------------
__global__ __launch_bounds__(256, 4)
void attn_fwd(const unsigned short* __restrict__ Q,   // [32][2048][64] (pre-scaled)
              const unsigned short* __restrict__ Kk,  // [32][2048][64]
              const unsigned short* __restrict__ Vt,  // [32][64][2048]
              unsigned short* __restrict__ O) {       // [4096][1024] (B,S,E)
    __shared__ unsigned short Ks[2][64 * 64];    // [key][d] swizzled, 2x8KB
    __shared__ unsigned short Vs[2][64 * 64];    // [d][key] swizzled, 2x8KB
    __shared__ unsigned short Ps[4 * 16 * 64];   // per-wave P [16 q][64 key] swizzled, 8KB

    const int tid = threadIdx.x;
    const int wid = tid >> 6, lane = tid & 63;

    // XCD-chunked bijective swizzle: 1024 blocks, 8 XCDs, 128 blocks/XCD.
    // Each XCD covers bh in [xcd*4, xcd*4+4) -> K/V working set 2MB <= L2.
    const int bid = blockIdx.x;
    const int swzb = (bid & 7) * 128 + (bid >> 3);
    const int bh = swzb >> 5;                    // [0,32)
    const int qt = swzb & 31;                    // [0,32)
    const int b = bh >> 4, h = bh & 15;
    const int q0 = qt * 64 + wid * 16;           // first q row for this wave

    const char* Qb  = (const char*)(Q  + (size_t)bh * 2048 * 64);
    const char* Kb  = (const char*)(Kk + (size_t)bh * 2048 * 64);
    const char* Vtb = (const char*)(Vt + (size_t)bh * 64 * 2048);
    char* PsW = (char*)Ps + wid * 2048;          // this wave's P region (16*64*2B)

    const int q = lane & 15, g = lane >> 4;
    const int qswz = (q & 7) << 4;

    // Q fragments: vector index q, k-elems = kf*32 + g*8 .. +8
    s16x8 aq[2];
#pragma unroll
    for (int kf = 0; kf < 2; ++kf)
        aq[kf] = *(const s16x8*)(Qb + (size_t)(q0 + q) * 128 + (kf * 32 + g * 8) * 2);

    f32x4 o_acc[4] = {};
    f32x4 l_acc = {};
    s16x8 ones;
#pragma unroll
    for (int j = 0; j < 8; ++j) ones[j] = (short)0x3F80;  // bf16 1.0

    // stage K chunk [64 keys][64 d] and Vt chunk [64 d][64 keys] into buf.
    // LDS rows are 128B; logical byte cb of row stored at (cb ^ ((row&7)<<4)).
    auto stage = [&](int kc, int buf) {
#pragma unroll
        for (int i = 0; i < 2; ++i) {
            const int lb = (wid * 2 + i) * 1024;
            const int row = (lb >> 7) + (lane >> 3);
            const int inrow = (lane & 7) * 16;
            const int srcin = inrow ^ ((row & 7) << 4);
            const char* gk = Kb + (size_t)(kc * 64 + row) * 128 + srcin;
            __builtin_amdgcn_global_load_lds(AS1C(gk), AS3((char*)Ks[buf] + lb), 16, 0, 0);
            const char* gv = Vtb + (size_t)row * 4096 + kc * 128 + srcin;
            __builtin_amdgcn_global_load_lds(AS1C(gv), AS3((char*)Vs[buf] + lb), 16, 0, 0);
        }
    };

    stage(0, 0);
    __syncthreads();

    for (int kc = 0; kc < 32; ++kc) {
        const int cur = kc & 1;
        if (kc < 31) stage(kc + 1, cur ^ 1);   // prefetch next chunk

        // ---- S^T = K Q^T - 16 (C-init does the subtract) ----
        // sacc[nf]: value at (key = nf*16 + 4g + r, q-col = q)
        f32x4 sacc[4];
#pragma unroll
        for (int nf = 0; nf < 4; ++nf) sacc[nf] = f32x4{-16.f, -16.f, -16.f, -16.f};
#pragma unroll
        for (int kf = 0; kf < 2; ++kf) {
            s16x8 bk[4];
#pragma unroll
            for (int nf = 0; nf < 4; ++nf) {
                const int key = nf * 16 + q;
                bk[nf] = *(const s16x8*)((const char*)Ks[cur] + key * 128 +
                                         (((kf * 32 + g * 8) * 2) ^ ((key & 7) << 4)));
            }
#pragma unroll
            for (int nf = 0; nf < 4; ++nf)
                sacc[nf] = __builtin_amdgcn_mfma_f32_16x16x32_bf16(bk[nf], aq[kf], sacc[nf], 0, 0, 0);
        }

        // ---- P = exp2(S), pack pairs (v_cvt_pk_bf16_f32), ds_write_b64 ----
        // lane holds keys 16nf+4g+r (r=0..3) for q-row q -> one 8B store per nf.
        {
            char* pbase = PsW + q * 128;
#pragma unroll
            for (int nf = 0; nf < 4; ++nf) {
                float2 lo2 = make_float2(fast_exp2(sacc[nf][0]), fast_exp2(sacc[nf][1]));
                float2 hi2 = make_float2(fast_exp2(sacc[nf][2]), fast_exp2(sacc[nf][3]));
                __hip_bfloat162 plo = __float22bfloat162_rn(lo2);
                __hip_bfloat162 phi = __float22bfloat162_rn(hi2);
                uint2 w;
                w.x = *(unsigned*)&plo;
                w.y = *(unsigned*)&phi;
                const int cb = (nf * 16 + 4 * g) * 2;   // byte of key 16nf+4g in row q
                *(uint2*)(pbase + (cb ^ qswz)) = w;
            }
        }

        // ---- l += P @ 1 ; O += P @ V ----
        s16x8 pa[2];
#pragma unroll
        for (int kf = 0; kf < 2; ++kf)
            pa[kf] = *(const s16x8*)(PsW + q * 128 + (((kf * 32 + g * 8) * 2) ^ qswz));
#pragma unroll
        for (int kf = 0; kf < 2; ++kf) {
            l_acc = __builtin_amdgcn_mfma_f32_16x16x32_bf16(pa[kf], ones, l_acc, 0, 0, 0);
            s16x8 bv[4];
#pragma unroll
            for (int df = 0; df < 4; ++df) {
                const int drow = df * 16 + q;
                bv[df] = *(const s16x8*)((const char*)Vs[cur] + drow * 128 +
                                         (((kf * 32 + g * 8) * 2) ^ ((drow & 7) << 4)));
            }
#pragma unroll
            for (int df = 0; df < 4; ++df)
                o_acc[df] = __builtin_amdgcn_mfma_f32_16x16x32_bf16(pa[kf], bv[df], o_acc[df], 0, 0, 0);
        }
        __syncthreads();   // all waves done reading bufs; next-chunk loads drained here
    }

    // ---- epilogue: O[b][s][h*64+d] = o_acc / l ----
    float inv[4];
#pragma unroll
    for (int r = 0; r < 4; ++r) inv[r] = 1.f / l_acc[r];
#pragma unroll
    for (int df = 0; df < 4; ++df) {
#pragma unroll
        for (int r = 0; r < 4; ++r) {
            const int srow = q0 + g * 4 + r;
            const int dcol = df * 16 + q;
            O[(size_t)(b * 2048 + srow) * 1024 + h * 64 + dcol] = f2bf(o_acc[df][r] * inv[r]);
        }
    }
}

// ---------------------------------------------------------------------------
extern "C" void kernel_launch(void* const* d_in, const int* in_sizes, int n_in,
                              void* d_out, int out_size, void* d_ws, size_t ws_size,
                              hipStream_t stream) {
    const float* query = (const float*)d_in[0];   // [2,2048,1024]
    const float* w_qkv = (const float*)d_in[1];   // [3072,1024]
    const float* b_qkv = (const float*)d_in[2];   // [3072]
    const float* w_out = (const float*)d_in[3];   // [1024,1024]
    const float* b_out = (const float*)d_in[4];   // [1024]
    float* out = (float*)d_out;                   // [2,2048,1024] fp32

    unsigned short* ws = (unsigned short*)d_ws;
    unsigned short* Xbf    = ws;                       // 4096*1024
    unsigned short* Wqkvbf = Xbf + 4096 * 1024;        // 3072*1024
    unsigned short* Woutbf = Wqkvbf + 3072 * 1024;     // 1024*1024
    unsigned short* Qw     = Woutbf + 1024 * 1024;     // 32*2048*64
    unsigned short* Kw     = Qw + 32 * 2048 * 64;
    unsigned short* Vtw    = Kw + 32 * 2048 * 64;
    unsigned short* Obf    = Vtw + 32 * 2048 * 64;     // 4096*1024

    const int na4 = 4096 * 1024 / 4, nb4 = 3072 * 1024 / 4, nc4 = 1024 * 1024 / 4;
    cvt_bf16_3<<<(na4 + nb4 + nc4 + 255) / 256, 256, 0, stream>>>(
        query, w_qkv, w_out, Xbf, Wqkvbf, Woutbf, na4, nb4, nc4);

    gemm_bt<0><<<dim3(3072 / 128, 4096 / 128), 256, 0, stream>>>(
        Xbf, Wqkvbf, b_qkv, nullptr, Qw, Kw, Vtw, 4096, 3072, 1024);

    attn_fwd<<<dim3(1024), 256, 0, stream>>>(Qw, Kw, Vtw, Obf);

    gemm_bt<1><<<dim3(1024 / 128, 4096 / 128), 256, 0, stream>>>(
        Obf, Woutbf, b_out, out, nullptr, nullptr, nullptr, 4096, 1024, 1024);
}